// Round 4
// baseline (283.119 us; speedup 1.0000x reference)
//
#include <hip/hip_runtime.h>
#include <hip/hip_bf16.h>
#include <stdint.h>

// out = x @ (W_shared + W_expert)^T + bias   (MoE collapses: positional routing,
// shared expert weights, normalized top-2 gate weights sum to 1)
static constexpr int Mdim = 16384;  // T = B*N tokens
static constexpr int Ndim = 1024;
static constexpr int Kdim = 1024;
static constexpr int BM = 128, BN = 128;
static constexpr int PK = 256;          // K per LDS-resident A-panel phase
static constexpr int NPH = Kdim / PK;   // 4 phases
static constexpr int KS = PK / 32;      // 8 barrier-free ksteps per phase

typedef __attribute__((ext_vector_type(8))) __bf16 bf16x8;
typedef __attribute__((ext_vector_type(4))) float f32x4;
typedef __attribute__((ext_vector_type(8))) unsigned short ushort8;

__device__ inline unsigned short f2bf_rn(float f) {
    union { float f; uint32_t u; } v; v.f = f;
    uint32_t u = v.u;
    uint32_t r = u + 0x7FFFu + ((u >> 16) & 1u);
    return (unsigned short)(r >> 16);
}

// two fp32 -> packed bf16 (round-half-up; ties-only deviation from RNE)
__device__ inline uint32_t pack_bf2(float a, float b) {
    union { float f; uint32_t u; } ua, ub;
    ua.f = a; ub.f = b;
    uint32_t x = ua.u + 0x8000u;
    uint32_t y = ub.u + 0x8000u;
    return (x >> 16) | (y & 0xFFFF0000u);
}

// Wc = bf16(W_shared + W_expert), 8 elems/thread
__global__ __launch_bounds__(256) void cvt_w_kernel(const float* __restrict__ ws,
                                                    const float* __restrict__ we,
                                                    unsigned short* __restrict__ wc) {
    const size_t i = ((size_t)blockIdx.x * 256 + threadIdx.x) * 8;
    const f32x4* p0 = (const f32x4*)(ws + i);
    const f32x4* p1 = (const f32x4*)(we + i);
    f32x4 a0 = p0[0], a1 = p0[1], b0 = p1[0], b1 = p1[1];
    ushort8 o;
    o[0] = f2bf_rn(a0[0] + b0[0]); o[1] = f2bf_rn(a0[1] + b0[1]);
    o[2] = f2bf_rn(a0[2] + b0[2]); o[3] = f2bf_rn(a0[3] + b0[3]);
    o[4] = f2bf_rn(a1[0] + b1[0]); o[5] = f2bf_rn(a1[1] + b1[1]);
    o[6] = f2bf_rn(a1[2] + b1[2]); o[7] = f2bf_rn(a1[3] + b1[3]);
    *(ushort8*)(wc + i) = o;
}

// Panel-resident GEMM. Per block (128m x 128n):
//  - A phase-panel (128 x 256 fp32 -> bf16) staged in LDS as 16-B chunks
//    indexed [kc][m ^ (kc&7)]  (kc = k/8). XOR swizzle -> conflict-free
//    staging writes AND fragment reads (bank = low-3-bits of swizzled m).
//  - B (bf16 W, L2-resident) streamed per-kstep straight into MFMA operand
//    registers via 16-B global loads: the 8-kstep inner loop has NO barriers,
//    so the compiler pipelines B loads across ksteps with fine-grained vmcnt.
//  - 2 barriers per phase, 8 total (vs 32 in the barrier-per-kstep structure).
// Wave tiling: wave w -> m in [w*32, w*32+32), all 128 n. acc = 2x8 f32x4.
__global__ __launch_bounds__(256, 2) void gemm_panel(const float* __restrict__ X,
                                                     const unsigned short* __restrict__ Bt,
                                                     const float* __restrict__ bias,
                                                     float* __restrict__ C) {
    __shared__ uint4 As[32 * 128];  // 64 KiB: chunk idx = kc*128 + (m ^ (kc&7))

    const int tid = threadIdx.x;
    const int wave = tid >> 6;
    const int lane = tid & 63;
    const int bid = blockIdx.x;
    const int bm = bid & 127;   // bm-fastest: all 8 bn-sharers of an X-stripe on one XCD
    const int bn = bid >> 7;
    const int fr = lane & 15;
    const int fq = lane >> 4;

    // ---- staging map: thread covers chunks (kc = tid&31, m = q*8 + (tid>>5)) ----
    const int skc = tid & 31;
    const int smb = tid >> 5;
    const int swz = skc & 7;
    const float* gX = X + ((size_t)(bm * BM) + smb) * Kdim + skc * 8;

    // ---- B stream base: lane reads Bt[n = bn*128 + j*16 + fr][k..k+8] ----
    const unsigned short* gB = Bt + ((size_t)(bn * BN) + fr) * Kdim + fq * 8;

    const int am = wave * 32 + fr;

    f32x4 acc[2][8] = {};

    for (int p = 0; p < NPH; ++p) {
        __syncthreads();  // all waves done reading the previous panel
#pragma unroll
        for (int q = 0; q < 16; ++q) {
            const float* src = gX + ((size_t)(q * 8)) * Kdim + p * PK;
            f32x4 v0 = *(const f32x4*)(src);
            f32x4 v1 = *(const f32x4*)(src + 4);
            uint4 c;
            c.x = pack_bf2(v0[0], v0[1]); c.y = pack_bf2(v0[2], v0[3]);
            c.z = pack_bf2(v1[0], v1[1]); c.w = pack_bf2(v1[2], v1[3]);
            As[skc * 128 + ((q * 8 + smb) ^ swz)] = c;
        }
        __syncthreads();  // panel p visible

        // barrier-free inner loop: 8 ksteps x (2 ds_read_b128 + 8 global 16B + 16 MFMA)
#pragma unroll
        for (int s = 0; s < KS; ++s) {
            const int kc = s * 4 + fq;
            bf16x8 af[2], bfr[8];
#pragma unroll
            for (int i = 0; i < 2; ++i)
                af[i] = *(const bf16x8*)&As[kc * 128 + ((am + i * 16) ^ (kc & 7))];
#pragma unroll
            for (int j = 0; j < 8; ++j)
                bfr[j] = *(const bf16x8*)(gB + (size_t)j * 16 * Kdim + p * PK + s * 32);
#pragma unroll
            for (int i = 0; i < 2; ++i)
#pragma unroll
                for (int j = 0; j < 8; ++j)
                    acc[i][j] = __builtin_amdgcn_mfma_f32_16x16x32_bf16(af[i], bfr[j], acc[i][j], 0, 0, 0);
        }
    }

    // Epilogue: C/D layout col = lane&15, row = (lane>>4)*4 + reg  [m89-verified]
#pragma unroll
    for (int j = 0; j < 8; ++j) {
        const int col = bn * BN + j * 16 + fr;
        const float bv = bias[col];
#pragma unroll
        for (int i = 0; i < 2; ++i) {
            const int row = bm * BM + wave * 32 + i * 16 + fq * 4;
            float* pc = C + (size_t)row * Ndim + col;
#pragma unroll
            for (int r = 0; r < 4; ++r)
                pc[(size_t)r * Ndim] = acc[i][j][r] + bv;
        }
    }
}

extern "C" void kernel_launch(void* const* d_in, const int* in_sizes, int n_in,
                              void* d_out, int out_size, void* d_ws, size_t ws_size,
                              hipStream_t stream) {
    // inputs: x, cond, mask, W_shared, W_expert, W_gate, bias
    const float* x    = (const float*)d_in[0];
    const float* Wsh  = (const float*)d_in[3];
    const float* Wex  = (const float*)d_in[4];
    const float* bias = (const float*)d_in[6];
    float* out = (float*)d_out;

    unsigned short* Wbf = (unsigned short*)d_ws;  // 1024*1024 bf16 = 2 MiB

    hipLaunchKernelGGL(cvt_w_kernel, dim3((Ndim * Kdim) / (256 * 8)), dim3(256), 0, stream,
                       Wsh, Wex, Wbf);
    hipLaunchKernelGGL(gemm_panel, dim3((Mdim / BM) * (Ndim / BN)), dim3(256), 0, stream,
                       x, Wbf, bias, out);
}